// Round 16
// baseline (123.213 us; speedup 1.0000x reference)
//
#include <hip/hip_runtime.h>
#include <hip/hip_bf16.h>

#define B_ 2
#define C_ 1024
#define S_ 2048
#define H_ 16
#define KDIM 1024

typedef __attribute__((ext_vector_type(8))) short short8_t;
typedef __attribute__((ext_vector_type(4))) float f32x4;
typedef __attribute__((ext_vector_type(16))) float f32x16;
typedef __attribute__((ext_vector_type(4))) int i32x4;

__device__ __forceinline__ void glds16(const void* g, void* l) {
  __builtin_amdgcn_global_load_lds((const __attribute__((address_space(1))) void*)g,
                                   (__attribute__((address_space(3))) void*)l, 16, 0, 0);
}

__device__ __forceinline__ unsigned short f2bf(float f) {
  __hip_bfloat16 h = __float2bfloat16(f);
  return __builtin_bit_cast(unsigned short, h);
}

__device__ __forceinline__ unsigned pkbf(float lo, float hi) {
  unsigned r;
  asm("v_cvt_pk_bf16_f32 %0, %1, %2" : "=v"(r) : "v"(lo), "v"(hi));
  return r;
}

__device__ __forceinline__ void plswap(unsigned &a, unsigned &b) {
  asm("v_permlane32_swap_b32 %0, %1" : "+v"(a), "+v"(b));
}

__device__ __forceinline__ float max3f(float a, float b, float c) {
  float r;
  asm("v_max3_f32 %0, %1, %2, %3" : "=v"(r) : "v"(a), "v"(b), "v"(c));
  return r;
}

// max over 16 values with v_max3 tree (8 ops)
__device__ __forceinline__ float max16v(const f32x16& v) {
  float a = max3f(v[0], v[1], v[2]);
  float b = max3f(v[3], v[4], v[5]);
  float c = max3f(v[6], v[7], v[8]);
  float d = max3f(v[9], v[10], v[11]);
  float e = max3f(v[12], v[13], v[14]);
  float f = max3f(a, b, v[15]);
  float g = max3f(c, d, e);
  return fmaxf(f, g);
}

// ---------------- fused: weight fp32->bf16 (4096 blocks) + stats1 (512) -------
__global__ __launch_bounds__(256) void cvt_stats(const float* __restrict__ a,
                                                 const float* __restrict__ b,
                                                 const float* __restrict__ c,
                                                 const float* __restrict__ d,
                                                 unsigned short* __restrict__ o,
                                                 const float* __restrict__ x,
                                                 float2* __restrict__ part) {
  int bid = blockIdx.x;
  int t = threadIdx.x;
  if (bid < 4096) {
    int g = bid >> 10;
    const float* src = (g == 0) ? a : (g == 1) ? b : (g == 2) ? c : d;
    int i = (bid & 1023) * 256 + t;
    float4 v = ((const float4*)src)[i];
    short4 r;
    r.x = (short)f2bf(v.x); r.y = (short)f2bf(v.y);
    r.z = (short)f2bf(v.z); r.w = (short)f2bf(v.w);
    ((short4*)(o))[(size_t)g * 262144 + i] = r;
    return;
  }
  int sb = bid - 4096;                               // 512 stats blocks
  int bb = sb >> 8, chunk = sb & 255;
  const float4* p = (const float4*)(x + (size_t)bb*(C_*S_) + (size_t)chunk*8192);
  float s = 0.f, q = 0.f;
#pragma unroll
  for (int i = 0; i < 8; ++i) {
    float4 v = p[t + i*256];
    s += v.x + v.y + v.z + v.w;
    q += v.x*v.x + v.y*v.y + v.z*v.z + v.w*v.w;
  }
#pragma unroll
  for (int dd = 1; dd < 64; dd <<= 1) { s += __shfl_xor(s, dd); q += __shfl_xor(q, dd); }
  __shared__ float2 wsum[4];
  if ((t & 63) == 0) wsum[t >> 6] = make_float2(s, q);
  __syncthreads();
  if (t == 0) {
    float S = 0.f, Q = 0.f;
    for (int i = 0; i < 4; ++i) { S += wsum[i].x; Q += wsum[i].y; }
    part[sb] = make_float2(S, Q);
  }
}

// ------- normalize + transpose (B,C,S)f32 -> (B,S,C)bf16, stats2 inlined ------
__global__ __launch_bounds__(256) void normt(const float* __restrict__ x,
                                             const float* __restrict__ gw,
                                             const float* __restrict__ gb,
                                             const float2* __restrict__ part,
                                             unsigned short* __restrict__ xt) {
  __shared__ short lds[64*72];
  __shared__ float2 wsum2[4];
  int bid = blockIdx.x;                              // 1024 blocks
  int b = bid >> 9, rem = bid & 511;
  int ct = rem >> 5, st = rem & 31;
  int t = threadIdx.x;

  // ---- inline stage-2 reduction over the 256 partials of batch b ----
  float2 pv = part[b*256 + t];
  float s = pv.x, q = pv.y;
#pragma unroll
  for (int d = 1; d < 64; d <<= 1) { s += __shfl_xor(s, d); q += __shfl_xor(q, d); }
  if ((t & 63) == 0) wsum2[t >> 6] = make_float2(s, q);
  __syncthreads();
  float S = 0.f, Q = 0.f;
#pragma unroll
  for (int i = 0; i < 4; ++i) { S += wsum2[i].x; Q += wsum2[i].y; }
  const float invN = 1.0f / (float)(C_*S_);
  float mean = S * invN;
  float rstd = rsqrtf(Q * invN - mean*mean + 1e-5f);

  int r = t >> 2, seg = t & 3;
  int c = ct*64 + r;
  float wsc = gw[c] * rstd;
  float bof = gb[c] - mean * wsc;
  const float4* src = (const float4*)(x + (size_t)b*(C_*S_) + (size_t)c*S_ + st*64 + seg*16);
#pragma unroll
  for (int j = 0; j < 4; ++j) {
    float4 v = src[j];
    int sl = seg*16 + j*4;
    lds[(sl+0)*72 + r] = (short)f2bf(v.x*wsc + bof);
    lds[(sl+1)*72 + r] = (short)f2bf(v.y*wsc + bof);
    lds[(sl+2)*72 + r] = (short)f2bf(v.z*wsc + bof);
    lds[(sl+3)*72 + r] = (short)f2bf(v.w*wsc + bof);
  }
  __syncthreads();
  int sl = t >> 2;
  __attribute__((aligned(16))) unsigned short tmp[16];
#pragma unroll
  for (int j = 0; j < 16; ++j) tmp[j] = (unsigned short)lds[sl*72 + seg*16 + j];
  unsigned short* dst = xt + ((size_t)b*S_ + st*64 + sl) * C_ + ct*64 + seg*16;
  *(short8_t*)dst       = *(const short8_t*)tmp;
  *(short8_t*)(dst + 8) = *(const short8_t*)(tmp + 8);
}

// ---------------- fused Q+K GEMM, 128x128 tile (m97 structure) ----------------
// A = x_b (4096 x 1024), Bm = [Wq; Wk] bf16 (2048 x 1024)
// out: q_b then k_b contiguous, each (B,H,S,D) bf16
__global__ __launch_bounds__(256)
void gemm_qk(const unsigned short* __restrict__ A,
             const unsigned short* __restrict__ Bm,
             const float* __restrict__ bq,
             const float* __restrict__ bk,
             unsigned short* __restrict__ outp) {
  __shared__ __attribute__((aligned(16))) short As[128*64];
  __shared__ __attribute__((aligned(16))) short Bs[128*64];
  int bid = blockIdx.x;                              // 512 blocks
  int sbid = (bid & 7) * 64 + (bid >> 3);            // XCD swizzle
  int bm = sbid >> 4, bn = sbid & 15;
  int m0 = bm << 7, n0 = bn << 7;
  int t = threadIdx.x, l = t & 63, wid = t >> 6;
  int wr = wid >> 1, wc = wid & 1;

  int rsb = wid*8 + (l >> 3);                        // staging row 0..31
  int slot_src = (l & 7) ^ (l >> 3);
  const unsigned short* a_src = A + (size_t)(m0 + rsb) * KDIM + slot_src * 8;
  const unsigned short* b_src = Bm + (size_t)(n0 + rsb) * KDIM + slot_src * 8;
  char* adst = (char*)As + wid*1024;
  char* bdst = (char*)Bs + wid*1024;

  f32x4 acc[4][4] = {};

  for (int kt = 0; kt < KDIM; kt += 64) {
    __syncthreads();
#pragma unroll
    for (int i = 0; i < 4; ++i) {
      glds16(a_src + (size_t)(i*32)*KDIM + kt, adst + i*4096);
      glds16(b_src + (size_t)(i*32)*KDIM + kt, bdst + i*4096);
    }
    __syncthreads();
#pragma unroll
    for (int kk = 0; kk < 2; ++kk) {
      short8_t af[4], bf[4];
#pragma unroll
      for (int mi = 0; mi < 4; ++mi) {
        int row = wr*64 + mi*16 + (l & 15);
        int slot = (kk*4 + (l >> 4)) ^ (row & 7);
        af[mi] = *(const short8_t*)((const char*)As + row*128 + slot*16);
      }
#pragma unroll
      for (int ni = 0; ni < 4; ++ni) {
        int row = wc*64 + ni*16 + (l & 15);
        int slot = (kk*4 + (l >> 4)) ^ (row & 7);
        bf[ni] = *(const short8_t*)((const char*)Bs + row*128 + slot*16);
      }
#pragma unroll
      for (int mi = 0; mi < 4; ++mi)
#pragma unroll
        for (int ni = 0; ni < 4; ++ni)
          acc[mi][ni] = __builtin_amdgcn_mfma_f32_16x16x32_bf16(af[mi], bf[ni], acc[mi][ni], 0, 0, 0);
    }
  }

  int gcol0 = n0 + wc*64;                            // uniform per wave
  const float* bp = (gcol0 & 1024) ? bk : bq;
  unsigned short* ob = outp + ((gcol0 & 1024) ? 4194304u : 0u);
  int hd0 = gcol0 & 1023;
#pragma unroll
  for (int mi = 0; mi < 4; ++mi)
#pragma unroll
    for (int ni = 0; ni < 4; ++ni)
#pragma unroll
      for (int r = 0; r < 4; ++r) {
        int gm = m0 + wr*64 + mi*16 + ((l >> 4) << 2) + r;
        int hd = hd0 + ni*16 + (l & 15);
        float v = acc[mi][ni][r] + bp[hd];
        size_t off = ((size_t)((gm >> 11)*H_ + (hd >> 6)) * S_ + (gm & 2047)) * 64 + (hd & 63);
        ob[off] = f2bf(v);
      }
}

// ---------------- V projection GEMM, 128x128 tile, 8 waves ----------------
// A = wv_b (1024 x 1024), Bm = x_b (4096 x 1024)
// out bf16 (B,C,S) = A.Bm^T + bv (rows = c_out)
__global__ __launch_bounds__(512)
void gemm_v(const unsigned short* __restrict__ A,
            const unsigned short* __restrict__ Bm,
            const float* __restrict__ bias,
            unsigned short* __restrict__ outp) {
  __shared__ __attribute__((aligned(16))) short As[128*64];
  __shared__ __attribute__((aligned(16))) short Bs[128*64];
  int bid = blockIdx.x;                              // 256 blocks
  int sbid = (bid & 7) * 32 + (bid >> 3);            // XCD swizzle
  int bm = sbid & 7, bn = sbid >> 3;                 // 8 x 32 tiles
  int m0 = bm << 7, n0 = bn << 7;
  int t = threadIdx.x, l = t & 63, wid = t >> 6;     // 8 waves
  int wr = wid >> 2, wc = wid & 3;                   // 2 x 4 wave grid

  int rsb = wid*8 + (l >> 3);                        // staging rows 0..63
  int slot_src = (l & 7) ^ (l >> 3);
  const unsigned short* a_src = A + (size_t)(m0 + rsb) * KDIM + slot_src * 8;
  const unsigned short* b_src = Bm + (size_t)(n0 + rsb) * KDIM + slot_src * 8;
  char* adst = (char*)As + wid*1024;
  char* bdst = (char*)Bs + wid*1024;

  f32x4 acc[4][2] = {};

  for (int kt = 0; kt < KDIM; kt += 64) {
    __syncthreads();
    glds16(a_src + kt, adst);
    glds16(a_src + (size_t)64*KDIM + kt, adst + 8192);
    glds16(b_src + kt, bdst);
    glds16(b_src + (size_t)64*KDIM + kt, bdst + 8192);
    __syncthreads();
#pragma unroll
    for (int kk = 0; kk < 2; ++kk) {
      short8_t af[4], bf[2];
#pragma unroll
      for (int mi = 0; mi < 4; ++mi) {
        int row = wr*64 + mi*16 + (l & 15);
        int slot = (kk*4 + (l >> 4)) ^ (row & 7);
        af[mi] = *(const short8_t*)((const char*)As + row*128 + slot*16);
      }
#pragma unroll
      for (int ni = 0; ni < 2; ++ni) {
        int row = wc*32 + ni*16 + (l & 15);
        int slot = (kk*4 + (l >> 4)) ^ (row & 7);
        bf[ni] = *(const short8_t*)((const char*)Bs + row*128 + slot*16);
      }
#pragma unroll
      for (int mi = 0; mi < 4; ++mi)
#pragma unroll
        for (int ni = 0; ni < 2; ++ni)
          acc[mi][ni] = __builtin_amdgcn_mfma_f32_16x16x32_bf16(af[mi], bf[ni], acc[mi][ni], 0, 0, 0);
    }
  }

#pragma unroll
  for (int mi = 0; mi < 4; ++mi)
#pragma unroll
    for (int ni = 0; ni < 2; ++ni)
#pragma unroll
      for (int r = 0; r < 4; ++r) {
        int gm = m0 + wr*64 + mi*16 + ((l >> 4) << 2) + r;
        int gn = n0 + wc*32 + ni*16 + (l & 15);
        float v = acc[mi][ni][r] + bias[gm];
        size_t off = (size_t)(gn >> 11) * ((size_t)C_*S_) + (size_t)gm * S_ + (gn & 2047);
        outp[off] = f2bf(v);
      }
}

// ---------------- NT GEMM (O-projection): out f32 (B,C,S) + bias + resid -----
__global__ __launch_bounds__(256)
void gemm_nt2(const unsigned short* __restrict__ A,
              const unsigned short* __restrict__ Bm,
              const float* __restrict__ bias,
              const float* __restrict__ resid,
              float* __restrict__ outp,
              int nbn) {
  __shared__ __attribute__((aligned(16))) short As[64*64];
  __shared__ __attribute__((aligned(16))) short Bs[128*64];
  int nwg = gridDim.x;
  int bid = blockIdx.x;
  int cpx = nwg >> 3;                                // grid % 8 == 0
  int sbid = (bid & 7) * cpx + (bid >> 3);
  int bm = sbid / nbn, bn = sbid % nbn;
  int m0 = bm << 6, n0 = bn << 7;
  int t = threadIdx.x;
  int l = t & 63, wid = t >> 6;

  int r_st = t >> 3;                                 // 0..31
  int slot_src = (t & 7) ^ (r_st & 7);               // pre-swizzled source slot
  const unsigned short* a_src = A + (size_t)(m0 + r_st) * KDIM + slot_src * 8;
  const unsigned short* b_src = Bm + (size_t)(n0 + r_st) * KDIM + slot_src * 8;
  char* As_base = (char*)As + wid*1024;
  char* Bs_base = (char*)Bs + wid*1024;

  f32x4 acc[4][2] = {};

  for (int kt = 0; kt < KDIM; kt += 64) {
    __syncthreads();
    glds16(a_src + kt, As_base);
    glds16(a_src + (size_t)32*KDIM + kt, As_base + 4096);
#pragma unroll
    for (int i = 0; i < 4; ++i)
      glds16(b_src + (size_t)(i*32)*KDIM + kt, Bs_base + i*4096);
    __syncthreads();
#pragma unroll
    for (int kk = 0; kk < 2; ++kk) {
      short8_t af[4], bfr[2];
#pragma unroll
      for (int mi = 0; mi < 4; ++mi) {
        int row = mi*16 + (l & 15);
        int slot = (kk*4 + (l >> 4)) ^ (row & 7);
        af[mi] = *(const short8_t*)((const char*)As + row*128 + slot*16);
      }
#pragma unroll
      for (int ni = 0; ni < 2; ++ni) {
        int row = wid*32 + ni*16 + (l & 15);
        int slot = (kk*4 + (l >> 4)) ^ (row & 7);
        bfr[ni] = *(const short8_t*)((const char*)Bs + row*128 + slot*16);
      }
#pragma unroll
      for (int mi = 0; mi < 4; ++mi)
#pragma unroll
        for (int ni = 0; ni < 2; ++ni)
          acc[mi][ni] = __builtin_amdgcn_mfma_f32_16x16x32_bf16(af[mi], bfr[ni], acc[mi][ni], 0, 0, 0);
    }
  }

#pragma unroll
  for (int mi = 0; mi < 4; ++mi) {
#pragma unroll
    for (int ni = 0; ni < 2; ++ni) {
#pragma unroll
      for (int r = 0; r < 4; ++r) {
        int gm = m0 + mi*16 + ((l >> 4) << 2) + r;
        int gn = n0 + wid*32 + ni*16 + (l & 15);
        float v = acc[mi][ni][r] + bias[gm];
        size_t off = (size_t)(gn >> 11) * ((size_t)C_*S_) + (size_t)gm * S_ + (gn & 2047);
        outp[off] = v + resid[off];
      }
    }
  }
}

// ---------------- flash attention, swapped 32x32, split-KV 8-wave -------------
// Q,K: (B,H,S,D) bf16; Vt: (B,H,D,S) bf16; out ao: (B,S,C) bf16
__global__ __launch_bounds__(512, 4)
void attn_kernel(const unsigned short* __restrict__ Q,
                 const unsigned short* __restrict__ Kt,
                 const unsigned short* __restrict__ Vt,
                 const int* __restrict__ mask,
                 unsigned short* __restrict__ outp) {
  // layout: K: quad*16384 + buf*8192 + row*128 + slot*16 ; V: +32768 same
  __shared__ __attribute__((aligned(16))) char lds[65536];
  __shared__ __attribute__((aligned(8)))  unsigned char maskb[256];
  __shared__ int tflag[32];

  int bid = blockIdx.x;                              // 512 blocks
  int bid2 = (bid & 7) * 64 + (bid >> 3);            // XCD swizzle (bijective)
  int bh = bid2 >> 4, qt = bid2 & 15;
  int b = bh >> 4, h = bh & 15;
  int t = threadIdx.x, l = t & 63, wid = t >> 6;
  int quad = wid >> 2, qw = wid & 3;
  int hh = l >> 5;                                   // half-lane index

  // ---- mask prologue: thread t<256 packs ints [8t, 8t+8) into byte t ----
  if (t < 256) {
    const i32x4* mp = (const i32x4*)(mask + b * S_) + t * 2;
    i32x4 m0 = mp[0], m1 = mp[1];
    unsigned by = (unsigned)(m0[0]!=0) | ((unsigned)(m0[1]!=0)<<1) | ((unsigned)(m0[2]!=0)<<2) | ((unsigned)(m0[3]!=0)<<3)
                | ((unsigned)(m1[0]!=0)<<4) | ((unsigned)(m1[1]!=0)<<5) | ((unsigned)(m1[2]!=0)<<6) | ((unsigned)(m1[3]!=0)<<7);
    maskb[t] = (unsigned char)by;
  }
  __syncthreads();
  if (t < 32) {
    unsigned long long v = ((const unsigned long long*)maskb)[t];
    tflag[t] = (v == 0xFFFFFFFFFFFFFFFFull) ? 1 : 0;
  }
  // visible after the first tile barrier

  // ---- Q fragments (B-operand): q-col = l&31, d = 16c + 8hh + j ----
  int q0 = qt*128 + qw*32;
  const unsigned short* qp = Q + ((size_t)bh * S_ + q0 + (l & 31)) * 64 + hh * 8;
  short8_t qf[4];
#pragma unroll
  for (int c = 0; c < 4; ++c) qf[c] = *(const short8_t*)(qp + c*16);

  // ---- staging: wave stages 16 K-rows + 16 V-rows of its quad's tile ----
  int kbase = quad << 10;
  int row_st = qw*16 + (l >> 3);
  int slot_st = (l & 7) ^ (l >> 3);
  const unsigned short* kp = Kt + ((size_t)bh * S_ + kbase + row_st) * 64 + slot_st * 8;
  const unsigned short* vp = Vt + ((size_t)bh * 64 + row_st) * S_ + kbase + slot_st * 8;
  char* kdst = lds + quad*16384 + qw*2048;
  char* vdst = kdst + 32768;

  // ---- ds-read byte offsets (tile-invariant; buf parity folds to imm) ----
  unsigned ko[8];
#pragma unroll
  for (int c = 0; c < 4; ++c) {
    unsigned slot = (unsigned)((c*2 + hh) ^ (l & 7)) * 16u;
    ko[c]   = (unsigned)(quad*16384) + (unsigned)(l & 31)*128u + slot;
    ko[c+4] = ko[c] + 4096u;
  }

  const short8_t vones = {0x3F80, 0x3F80, 0x3F80, 0x3F80, 0x3F80, 0x3F80, 0x3F80, 0x3F80};
  const float SC = 0.18033688011112042f;             // (1/8) * log2(e)
  float m_run = 0.f, msc = 0.f;
  f32x16 oc0 = {}, oc1 = {}, lsum = {};

  // prologue: stage tile 0 into buffer 0
  glds16(kp,                kdst);
  glds16(kp + 8*64,         kdst + 1024);
  glds16(vp,                vdst);
  glds16(vp + (size_t)8*S_, vdst + 1024);
  const unsigned short* kn = kp + 64*64;
  const unsigned short* vn = vp + 64;
  int lt = 0;

#define ATILE(BUF)                                                              \
  do {                                                                          \
    __syncthreads();                                                            \
    glds16(kn,                kdst + ((BUF)^1)*8192);                           \
    glds16(kn + 8*64,         kdst + ((BUF)^1)*8192 + 1024);                    \
    glds16(vn,                vdst + ((BUF)^1)*8192);                           \
    glds16(vn + (size_t)8*S_, vdst + ((BUF)^1)*8192 + 1024);                    \
    kn += 4096; vn += 64;                                                       \
    f32x16 st0 = {}, st1 = {};                                                  \
    __builtin_amdgcn_s_setprio(1);                                              \
    _Pragma("unroll")                                                           \
    for (int c = 0; c < 4; ++c) {                                               \
      short8_t kf0 = *(const short8_t*)(lds + ko[c]   + (BUF)*8192);            \
      short8_t kf1 = *(const short8_t*)(lds + ko[c+4] + (BUF)*8192);            \
      st0 = __builtin_amdgcn_mfma_f32_32x32x16_bf16(kf0, qf[c], st0, 0, 0, 0);  \
      st1 = __builtin_amdgcn_mfma_f32_32x32x16_bf16(kf1, qf[c], st1, 0, 0, 0);  \
    }                                                                           \
    __builtin_amdgcn_s_setprio(0);                                              \
    _Pragma("unroll")                                                           \
    for (int r = 0; r < 16; ++r) {                                              \
      st0[r] = __builtin_amdgcn_exp2f(fmaf(st0[r], SC, -msc));                  \
      st1[r] = __builtin_amdgcn_exp2f(fmaf(st1[r], SC, -msc));                  \
    }                                                                           \
    if (!tflag[(kbase >> 6) + lt]) {                                            \
      _Pragma("unroll")                                                         \
      for (int r = 0; r < 16; ++r) {                                            \
        int kl = kbase + lt*64 + (r & 3) + 8*(r >> 2) + 4*hh;                   \
        if (!((maskb[kl >> 3] >> (kl & 7)) & 1)) st0[r] = 0.f;                  \
        kl += 32;                                                               \
        if (!((maskb[kl >> 3] >> (kl & 7)) & 1)) st1[r] = 0.f;                  \
      }                                                                         \
    }                                                                           \
    float pmax = fmaxf(max16v(st0), max16v(st1));                               \
    short8_t pa[4];                                                             \
    {                                                                           \
      unsigned a0 = pkbf(st0[0],  st0[1]),  b0 = pkbf(st0[4],  st0[5]);         \
      unsigned a1 = pkbf(st0[2],  st0[3]),  b1 = pkbf(st0[6],  st0[7]);         \
      plswap(a0, b0); plswap(a1, b1);                                           \
      i32x4 w0 = {(int)a0, (int)a1, (int)b0, (int)b1};                          \
      pa[0] = __builtin_bit_cast(short8_t, w0);                                 \
      unsigned a2 = pkbf(st0[8],  st0[9]),  b2 = pkbf(st0[12], st0[13]);        \
      unsigned a3 = pkbf(st0[10], st0[11]), b3 = pkbf(st0[14], st0[15]);        \
      plswap(a2, b2); plswap(a3, b3);                                           \
      i32x4 w1 = {(int)a2, (int)a3, (int)b2, (int)b3};                          \
      pa[1] = __builtin_bit_cast(short8_t, w1);                                 \
      unsigned a4 = pkbf(st1[0],  st1[1]),  b4 = pkbf(st1[4],  st1[5]);         \
      unsigned a5 = pkbf(st1[2],  st1[3]),  b5 = pkbf(st1[6],  st1[7]);         \
      plswap(a4, b4); plswap(a5, b5);                                           \
      i32x4 w2 = {(int)a4, (int)a5, (int)b4, (int)b5};                          \
      pa[2] = __builtin_bit_cast(short8_t, w2);                                 \
      unsigned a6 = pkbf(st1[8],  st1[9]),  b6 = pkbf(st1[12], st1[13]);        \
      unsigned a7 = pkbf(st1[10], st1[11]), b7 = pkbf(st1[14], st1[15]);        \
      plswap(a6, b6); plswap(a7, b7);                                           \
      i32x4 w3 = {(int)a6, (int)a7, (int)b6, (int)b7};                          \
      pa[3] = __builtin_bit_cast(short8_t, w3);                                 \
    }                                                                           \
    __builtin_amdgcn_s_setprio(1);                                              \
    _Pragma("unroll")                                                           \
    for (int kc = 0; kc < 4; ++kc) {                                            \
      short8_t vf0 = *(const short8_t*)(lds + ko[kc]   + 32768 + (BUF)*8192);   \
      short8_t vf1 = *(const short8_t*)(lds + ko[kc+4] + 32768 + (BUF)*8192);   \
      oc0 = __builtin_amdgcn_mfma_f32_32x32x16_bf16(vf0, pa[kc], oc0, 0, 0, 0); \
      oc1 = __builtin_amdgcn_mfma_f32_32x32x16_bf16(vf1, pa[kc], oc1, 0, 0, 0); \
      lsum = __builtin_amdgcn_mfma_f32_32x32x16_bf16(vones, pa[kc], lsum, 0, 0, 0); \
    }                                                                           \
    __builtin_amdgcn_s_setprio(0);                                              \
    if (__any(pmax > 148.0f)) {                                                 \
      float pm = fmaxf(pmax, __shfl_xor(pmax, 32));                             \
      float smax = (__log2f(pm) + msc) / SC;                                    \
      float nm = fmaxf(m_run, smax);                                            \
      float fac = __builtin_amdgcn_exp2f((m_run - nm) * SC);                    \
      _Pragma("unroll")                                                         \
      for (int r = 0; r < 16; ++r) { oc0[r] *= fac; oc1[r] *= fac; lsum[r] *= fac; } \
      m_run = nm; msc = nm * SC;                                                \
    }                                                                           \
    ++lt;                                                                       \
  } while (0)

  for (int tp = 0; tp < 8; ++tp) {
    ATILE(0);
    ATILE(1);
  }
#undef ATILE

  // ---- merge epilogue: quad1 -> LDS, quad0 combines + stores ----
  __syncthreads();                                   // also drains garbage glds
  if (quad == 1) {
    char* obuf = lds + qw*8192 + l*128;
#pragma unroll
    for (int j = 0; j < 4; ++j) {
      f32x4 u0 = { oc0[4*j], oc0[4*j+1], oc0[4*j+2], oc0[4*j+3] };
      *(f32x4*)(obuf + ((j ^ (l & 7)) * 16)) = u0;
      f32x4 u1 = { oc1[4*j], oc1[4*j+1], oc1[4*j+2], oc1[4*j+3] };
      *(f32x4*)(obuf + (((j+4) ^ (l & 7)) * 16)) = u1;
    }
    *(float2*)(lds + 32768 + (qw*64 + l)*8) = make_float2(lsum[0], m_run);
  }
  __syncthreads();
  if (quad == 0) {
    float2 lm1 = *(const float2*)(lds + 32768 + (qw*64 + l)*8);
    float M  = fmaxf(m_run, lm1.y);
    float a0 = __builtin_amdgcn_exp2f((m_run - M) * SC);
    float a1 = __builtin_amdgcn_exp2f((lm1.y - M) * SC);
    float lc = lsum[0] * a0 + lm1.x * a1;
    float inv = 1.f / lc;
    float s0 = a0 * inv, s1 = a1 * inv;
    const char* obuf = lds + qw*8192 + l*128;
#pragma unroll
    for (int j = 0; j < 4; ++j) {
      f32x4 u0 = *(const f32x4*)(obuf + ((j ^ (l & 7)) * 16));
      oc0[4*j]   = oc0[4*j]  *s0 + u0[0]*s1;
      oc0[4*j+1] = oc0[4*j+1]*s0 + u0[1]*s1;
      oc0[4*j+2] = oc0[4*j+2]*s0 + u0[2]*s1;
      oc0[4*j+3] = oc0[4*j+3]*s0 + u0[3]*s1;
      f32x4 u1 = *(const f32x4*)(obuf + (((j+4) ^ (l & 7)) * 16));
      oc1[4*j]   = oc1[4*j]  *s0 + u1[0]*s1;
      oc1[4*j+1] = oc1[4*j+1]*s0 + u1[1]*s1;
      oc1[4*j+2] = oc1[4*j+2]*s0 + u1[2]*s1;
      oc1[4*j+3] = oc1[4*j+3]*s0 + u1[3]*s1;
    }

    unsigned short* obase = outp + ((size_t)b * S_ + q0 + (l & 31)) * C_ + h*64 + hh*8;
#pragma unroll
    for (int dt = 0; dt < 2; ++dt) {
      const f32x16& oc = dt ? oc1 : oc0;
      unsigned a0w = pkbf(oc[0],  oc[1]),  b0w = pkbf(oc[4],  oc[5]);
      unsigned a1w = pkbf(oc[2],  oc[3]),  b1w = pkbf(oc[6],  oc[7]);
      plswap(a0w, b0w); plswap(a1w, b1w);
      i32x4 w0 = {(int)a0w, (int)a1w, (int)b0w, (int)b1w};
      *(i32x4*)(obase + dt*32) = w0;
      unsigned a2w = pkbf(oc[8],  oc[9]),  b2w = pkbf(oc[12], oc[13]);
      unsigned a3w = pkbf(oc[10], oc[11]), b3w = pkbf(oc[14], oc[15]);
      plswap(a2w, b2w); plswap(a3w, b3w);
      i32x4 w1 = {(int)a2w, (int)a3w, (int)b2w, (int)b3w};
      *(i32x4*)(obase + dt*32 + 16) = w1;
    }
  }
}

// ---------------- launcher ----------------
extern "C" void kernel_launch(void* const* d_in, const int* in_sizes, int n_in,
                              void* d_out, int out_size, void* d_ws, size_t ws_size,
                              hipStream_t stream) {
  const float* hs = (const float*)d_in[0];
  const int*   msk = (const int*)d_in[1];
  const float* gw = (const float*)d_in[2];
  const float* gb = (const float*)d_in[3];
  const float* Wq = (const float*)d_in[4];
  const float* bq = (const float*)d_in[5];
  const float* Wk = (const float*)d_in[6];
  const float* bk = (const float*)d_in[7];
  const float* Wv = (const float*)d_in[8];
  const float* bv = (const float*)d_in[9];
  const float* Wo = (const float*)d_in[10];
  const float* bo = (const float*)d_in[11];

  char* ws = (char*)d_ws;
  float2* part  = (float2*)(ws + 256);
  unsigned short* wq_b = (unsigned short*)(ws + 8192);
  unsigned short* wk_b = wq_b + 1048576;
  unsigned short* wv_b = wk_b + 1048576;
  unsigned short* wo_b = wv_b + 1048576;
  unsigned short* x_b  = wo_b + 1048576;     // (B,S,C) bf16
  unsigned short* q_b  = x_b  + 4194304;     // (B,H,S,D)
  unsigned short* k_b  = q_b  + 4194304;     // (B,H,S,D)
  unsigned short* vt_b = k_b  + 4194304;     // (B,H,D,S)
  unsigned short* ao_b = vt_b + 4194304;     // (B,S,C)

  cvt_stats<<<4608, 256, 0, stream>>>(Wq, Wk, Wv, Wo, wq_b, hs, part);
  normt<<<1024, 256, 0, stream>>>(hs, gw, gb, part, x_b);

  gemm_qk<<<512, 256, 0, stream>>>(x_b, wq_b, bq, bk, q_b);
  gemm_v<<<256, 512, 0, stream>>>(wv_b, x_b, bv, vt_b);

  attn_kernel<<<512, 512, 0, stream>>>(q_b, k_b, vt_b, msk, ao_b);

  gemm_nt2<<<512, 256, 0, stream>>>(wo_b, ao_b, bo, hs, (float*)d_out, 32);
}

// Round 20
// 120.647 us; speedup vs baseline: 1.0213x; 1.0213x over previous
//
#include <hip/hip_runtime.h>
#include <hip/hip_bf16.h>

#define B_ 2
#define C_ 1024
#define S_ 2048
#define H_ 16
#define KDIM 1024

typedef __attribute__((ext_vector_type(8))) short short8_t;
typedef __attribute__((ext_vector_type(4))) float f32x4;
typedef __attribute__((ext_vector_type(16))) float f32x16;
typedef __attribute__((ext_vector_type(4))) int i32x4;

__device__ __forceinline__ void glds16(const void* g, void* l) {
  __builtin_amdgcn_global_load_lds((const __attribute__((address_space(1))) void*)g,
                                   (__attribute__((address_space(3))) void*)l, 16, 0, 0);
}

__device__ __forceinline__ unsigned short f2bf(float f) {
  __hip_bfloat16 h = __float2bfloat16(f);
  return __builtin_bit_cast(unsigned short, h);
}

__device__ __forceinline__ unsigned pkbf(float lo, float hi) {
  unsigned r;
  asm("v_cvt_pk_bf16_f32 %0, %1, %2" : "=v"(r) : "v"(lo), "v"(hi));
  return r;
}

__device__ __forceinline__ void plswap(unsigned &a, unsigned &b) {
  asm("v_permlane32_swap_b32 %0, %1" : "+v"(a), "+v"(b));
}

__device__ __forceinline__ float max3f(float a, float b, float c) {
  float r;
  asm("v_max3_f32 %0, %1, %2, %3" : "=v"(r) : "v"(a), "v"(b), "v"(c));
  return r;
}

// max over 16 values with v_max3 tree (8 ops)
__device__ __forceinline__ float max16v(const f32x16& v) {
  float a = max3f(v[0], v[1], v[2]);
  float b = max3f(v[3], v[4], v[5]);
  float c = max3f(v[6], v[7], v[8]);
  float d = max3f(v[9], v[10], v[11]);
  float e = max3f(v[12], v[13], v[14]);
  float f = max3f(a, b, v[15]);
  float g = max3f(c, d, e);
  return fmaxf(f, g);
}

// ---------------- fused: weight fp32->bf16 (4096 blocks) + stats1 (512) -------
__global__ __launch_bounds__(256) void cvt_stats(const float* __restrict__ a,
                                                 const float* __restrict__ b,
                                                 const float* __restrict__ c,
                                                 const float* __restrict__ d,
                                                 unsigned short* __restrict__ o,
                                                 const float* __restrict__ x,
                                                 float2* __restrict__ part) {
  int bid = blockIdx.x;
  int t = threadIdx.x;
  if (bid < 4096) {
    int g = bid >> 10;
    const float* src = (g == 0) ? a : (g == 1) ? b : (g == 2) ? c : d;
    int i = (bid & 1023) * 256 + t;
    float4 v = ((const float4*)src)[i];
    short4 r;
    r.x = (short)f2bf(v.x); r.y = (short)f2bf(v.y);
    r.z = (short)f2bf(v.z); r.w = (short)f2bf(v.w);
    ((short4*)(o))[(size_t)g * 262144 + i] = r;
    return;
  }
  int sb = bid - 4096;                               // 512 stats blocks
  int bb = sb >> 8, chunk = sb & 255;
  const float4* p = (const float4*)(x + (size_t)bb*(C_*S_) + (size_t)chunk*8192);
  float s = 0.f, q = 0.f;
#pragma unroll
  for (int i = 0; i < 8; ++i) {
    float4 v = p[t + i*256];
    s += v.x + v.y + v.z + v.w;
    q += v.x*v.x + v.y*v.y + v.z*v.z + v.w*v.w;
  }
#pragma unroll
  for (int dd = 1; dd < 64; dd <<= 1) { s += __shfl_xor(s, dd); q += __shfl_xor(q, dd); }
  __shared__ float2 wsum[4];
  if ((t & 63) == 0) wsum[t >> 6] = make_float2(s, q);
  __syncthreads();
  if (t == 0) {
    float S = 0.f, Q = 0.f;
    for (int i = 0; i < 4; ++i) { S += wsum[i].x; Q += wsum[i].y; }
    part[sb] = make_float2(S, Q);
  }
}

// ------- normalize + transpose (B,C,S)f32 -> (B,S,C)bf16, stats2 inlined ------
__global__ __launch_bounds__(256) void normt(const float* __restrict__ x,
                                             const float* __restrict__ gw,
                                             const float* __restrict__ gb,
                                             const float2* __restrict__ part,
                                             unsigned short* __restrict__ xt) {
  __shared__ short lds[64*72];
  __shared__ float2 wsum2[4];
  int bid = blockIdx.x;                              // 1024 blocks
  int b = bid >> 9, rem = bid & 511;
  int ct = rem >> 5, st = rem & 31;
  int t = threadIdx.x;

  // ---- inline stage-2 reduction over the 256 partials of batch b ----
  float2 pv = part[b*256 + t];
  float s = pv.x, q = pv.y;
#pragma unroll
  for (int d = 1; d < 64; d <<= 1) { s += __shfl_xor(s, d); q += __shfl_xor(q, d); }
  if ((t & 63) == 0) wsum2[t >> 6] = make_float2(s, q);
  __syncthreads();
  float S = 0.f, Q = 0.f;
#pragma unroll
  for (int i = 0; i < 4; ++i) { S += wsum2[i].x; Q += wsum2[i].y; }
  const float invN = 1.0f / (float)(C_*S_);
  float mean = S * invN;
  float rstd = rsqrtf(Q * invN - mean*mean + 1e-5f);

  int r = t >> 2, seg = t & 3;
  int c = ct*64 + r;
  float wsc = gw[c] * rstd;
  float bof = gb[c] - mean * wsc;
  const float4* src = (const float4*)(x + (size_t)b*(C_*S_) + (size_t)c*S_ + st*64 + seg*16);
#pragma unroll
  for (int j = 0; j < 4; ++j) {
    float4 v = src[j];
    int sl = seg*16 + j*4;
    lds[(sl+0)*72 + r] = (short)f2bf(v.x*wsc + bof);
    lds[(sl+1)*72 + r] = (short)f2bf(v.y*wsc + bof);
    lds[(sl+2)*72 + r] = (short)f2bf(v.z*wsc + bof);
    lds[(sl+3)*72 + r] = (short)f2bf(v.w*wsc + bof);
  }
  __syncthreads();
  int sl = t >> 2;
  __attribute__((aligned(16))) unsigned short tmp[16];
#pragma unroll
  for (int j = 0; j < 16; ++j) tmp[j] = (unsigned short)lds[sl*72 + seg*16 + j];
  unsigned short* dst = xt + ((size_t)b*S_ + st*64 + sl) * C_ + ct*64 + seg*16;
  *(short8_t*)dst       = *(const short8_t*)tmp;
  *(short8_t*)(dst + 8) = *(const short8_t*)(tmp + 8);
}

// ---------------- fused Q+K GEMM, 128x128 tile (m97 structure) ----------------
// A = x_b (4096 x 1024), Bm = [Wq; Wk] bf16 (2048 x 1024)
// out: q_b then k_b contiguous, each (B,H,S,D) bf16
__global__ __launch_bounds__(256)
void gemm_qk(const unsigned short* __restrict__ A,
             const unsigned short* __restrict__ Bm,
             const float* __restrict__ bq,
             const float* __restrict__ bk,
             unsigned short* __restrict__ outp) {
  __shared__ __attribute__((aligned(16))) short As[128*64];
  __shared__ __attribute__((aligned(16))) short Bs[128*64];
  int bid = blockIdx.x;                              // 512 blocks
  int sbid = (bid & 7) * 64 + (bid >> 3);            // XCD swizzle
  int bm = sbid >> 4, bn = sbid & 15;
  int m0 = bm << 7, n0 = bn << 7;
  int t = threadIdx.x, l = t & 63, wid = t >> 6;
  int wr = wid >> 1, wc = wid & 1;

  int rsb = wid*8 + (l >> 3);                        // staging row 0..31
  int slot_src = (l & 7) ^ (l >> 3);
  const unsigned short* a_src = A + (size_t)(m0 + rsb) * KDIM + slot_src * 8;
  const unsigned short* b_src = Bm + (size_t)(n0 + rsb) * KDIM + slot_src * 8;
  char* adst = (char*)As + wid*1024;
  char* bdst = (char*)Bs + wid*1024;

  f32x4 acc[4][4] = {};

  for (int kt = 0; kt < KDIM; kt += 64) {
    __syncthreads();
#pragma unroll
    for (int i = 0; i < 4; ++i) {
      glds16(a_src + (size_t)(i*32)*KDIM + kt, adst + i*4096);
      glds16(b_src + (size_t)(i*32)*KDIM + kt, bdst + i*4096);
    }
    __syncthreads();
#pragma unroll
    for (int kk = 0; kk < 2; ++kk) {
      short8_t af[4], bf[4];
#pragma unroll
      for (int mi = 0; mi < 4; ++mi) {
        int row = wr*64 + mi*16 + (l & 15);
        int slot = (kk*4 + (l >> 4)) ^ (row & 7);
        af[mi] = *(const short8_t*)((const char*)As + row*128 + slot*16);
      }
#pragma unroll
      for (int ni = 0; ni < 4; ++ni) {
        int row = wc*64 + ni*16 + (l & 15);
        int slot = (kk*4 + (l >> 4)) ^ (row & 7);
        bf[ni] = *(const short8_t*)((const char*)Bs + row*128 + slot*16);
      }
#pragma unroll
      for (int mi = 0; mi < 4; ++mi)
#pragma unroll
        for (int ni = 0; ni < 4; ++ni)
          acc[mi][ni] = __builtin_amdgcn_mfma_f32_16x16x32_bf16(af[mi], bf[ni], acc[mi][ni], 0, 0, 0);
    }
  }

  int gcol0 = n0 + wc*64;                            // uniform per wave
  const float* bp = (gcol0 & 1024) ? bk : bq;
  unsigned short* ob = outp + ((gcol0 & 1024) ? 4194304u : 0u);
  int hd0 = gcol0 & 1023;
#pragma unroll
  for (int mi = 0; mi < 4; ++mi)
#pragma unroll
    for (int ni = 0; ni < 4; ++ni)
#pragma unroll
      for (int r = 0; r < 4; ++r) {
        int gm = m0 + wr*64 + mi*16 + ((l >> 4) << 2) + r;
        int hd = hd0 + ni*16 + (l & 15);
        float v = acc[mi][ni][r] + bp[hd];
        size_t off = ((size_t)((gm >> 11)*H_ + (hd >> 6)) * S_ + (gm & 2047)) * 64 + (hd & 63);
        ob[off] = f2bf(v);
      }
}

// ---------------- NT GEMM: C[m,n] = sum_k A[m,k]*B[n,k] (K=1024) ----------------
// EPI 1: out bf16 (B,C,S) rows=c_out, bias[gm]  (V projection, A=Wv, B=x)
// EPI 2: out f32  (B,C,S) + bias[gm] + resid    (O projection, A=Wo, B=ao)
template<int EPI>
__global__ __launch_bounds__(256)
void gemm_nt(const unsigned short* __restrict__ A,
             const unsigned short* __restrict__ Bm,
             const float* __restrict__ bias,
             const float* __restrict__ resid,
             void* __restrict__ outp,
             int nbn) {
  __shared__ __attribute__((aligned(16))) short As[64*64];
  __shared__ __attribute__((aligned(16))) short Bs[128*64];
  int nwg = gridDim.x;
  int bid = blockIdx.x;
  int cpx = nwg >> 3;                                // grid % 8 == 0
  int sbid = (bid & 7) * cpx + (bid >> 3);
  int bm = sbid / nbn, bn = sbid % nbn;
  int m0 = bm << 6, n0 = bn << 7;
  int t = threadIdx.x;
  int l = t & 63, wid = t >> 6;

  int r_st = t >> 3;                                 // 0..31
  int slot_src = (t & 7) ^ (r_st & 7);               // pre-swizzled source slot
  const unsigned short* a_src = A + (size_t)(m0 + r_st) * KDIM + slot_src * 8;
  const unsigned short* b_src = Bm + (size_t)(n0 + r_st) * KDIM + slot_src * 8;
  char* As_base = (char*)As + wid*1024;
  char* Bs_base = (char*)Bs + wid*1024;

  f32x4 acc[4][2] = {};

  for (int kt = 0; kt < KDIM; kt += 64) {
    __syncthreads();
    glds16(a_src + kt, As_base);
    glds16(a_src + (size_t)32*KDIM + kt, As_base + 4096);
#pragma unroll
    for (int i = 0; i < 4; ++i)
      glds16(b_src + (size_t)(i*32)*KDIM + kt, Bs_base + i*4096);
    __syncthreads();
#pragma unroll
    for (int kk = 0; kk < 2; ++kk) {
      short8_t af[4], bfr[2];
#pragma unroll
      for (int mi = 0; mi < 4; ++mi) {
        int row = mi*16 + (l & 15);
        int slot = (kk*4 + (l >> 4)) ^ (row & 7);
        af[mi] = *(const short8_t*)((const char*)As + row*128 + slot*16);
      }
#pragma unroll
      for (int ni = 0; ni < 2; ++ni) {
        int row = wid*32 + ni*16 + (l & 15);
        int slot = (kk*4 + (l >> 4)) ^ (row & 7);
        bfr[ni] = *(const short8_t*)((const char*)Bs + row*128 + slot*16);
      }
#pragma unroll
      for (int mi = 0; mi < 4; ++mi)
#pragma unroll
        for (int ni = 0; ni < 2; ++ni)
          acc[mi][ni] = __builtin_amdgcn_mfma_f32_16x16x32_bf16(af[mi], bfr[ni], acc[mi][ni], 0, 0, 0);
    }
  }

#pragma unroll
  for (int mi = 0; mi < 4; ++mi) {
#pragma unroll
    for (int ni = 0; ni < 2; ++ni) {
#pragma unroll
      for (int r = 0; r < 4; ++r) {
        int gm = m0 + mi*16 + ((l >> 4) << 2) + r;
        int gn = n0 + wid*32 + ni*16 + (l & 15);
        float v = acc[mi][ni][r];
        v += bias[gm];
        size_t off = (size_t)(gn >> 11) * ((size_t)C_*S_) + (size_t)gm * S_ + (gn & 2047);
        if (EPI == 1) {
          ((unsigned short*)outp)[off] = f2bf(v);
        } else {
          ((float*)outp)[off] = v + resid[off];
        }
      }
    }
  }
}

// ---------------- flash attention, swapped 32x32, split-KV 8-wave -------------
// Q,K: (B,H,S,D) bf16; Vt: (B,H,D,S) bf16; out ao: (B,S,C) bf16
// Tail prefetch guarded (lt < 15): no in-flight glds at the epilogue barrier.
__global__ __launch_bounds__(512, 4)
void attn_kernel(const unsigned short* __restrict__ Q,
                 const unsigned short* __restrict__ Kt,
                 const unsigned short* __restrict__ Vt,
                 const int* __restrict__ mask,
                 unsigned short* __restrict__ outp) {
  // layout: K: quad*16384 + buf*8192 + row*128 + slot*16 ; V: +32768 same
  __shared__ __attribute__((aligned(16))) char lds[65536];
  __shared__ __attribute__((aligned(8)))  unsigned char maskb[256];
  __shared__ int tflag[32];

  int bid = blockIdx.x;                              // 512 blocks
  int bid2 = (bid & 7) * 64 + (bid >> 3);            // XCD swizzle (bijective)
  int bh = bid2 >> 4, qt = bid2 & 15;
  int b = bh >> 4, h = bh & 15;
  int t = threadIdx.x, l = t & 63, wid = t >> 6;
  int quad = wid >> 2, qw = wid & 3;
  int hh = l >> 5;                                   // half-lane index

  // ---- mask prologue: thread t<256 packs ints [8t, 8t+8) into byte t ----
  if (t < 256) {
    const i32x4* mp = (const i32x4*)(mask + b * S_) + t * 2;
    i32x4 m0 = mp[0], m1 = mp[1];
    unsigned by = (unsigned)(m0[0]!=0) | ((unsigned)(m0[1]!=0)<<1) | ((unsigned)(m0[2]!=0)<<2) | ((unsigned)(m0[3]!=0)<<3)
                | ((unsigned)(m1[0]!=0)<<4) | ((unsigned)(m1[1]!=0)<<5) | ((unsigned)(m1[2]!=0)<<6) | ((unsigned)(m1[3]!=0)<<7);
    maskb[t] = (unsigned char)by;
  }
  __syncthreads();
  if (t < 32) {
    unsigned long long v = ((const unsigned long long*)maskb)[t];
    tflag[t] = (v == 0xFFFFFFFFFFFFFFFFull) ? 1 : 0;
  }
  // visible after the first tile barrier

  // ---- Q fragments (B-operand): q-col = l&31, d = 16c + 8hh + j ----
  int q0 = qt*128 + qw*32;
  const unsigned short* qp = Q + ((size_t)bh * S_ + q0 + (l & 31)) * 64 + hh * 8;
  short8_t qf[4];
#pragma unroll
  for (int c = 0; c < 4; ++c) qf[c] = *(const short8_t*)(qp + c*16);

  // ---- staging: wave stages 16 K-rows + 16 V-rows of its quad's tile ----
  int kbase = quad << 10;
  int row_st = qw*16 + (l >> 3);
  int slot_st = (l & 7) ^ (l >> 3);
  const unsigned short* kp = Kt + ((size_t)bh * S_ + kbase + row_st) * 64 + slot_st * 8;
  const unsigned short* vp = Vt + ((size_t)bh * 64 + row_st) * S_ + kbase + slot_st * 8;
  char* kdst = lds + quad*16384 + qw*2048;
  char* vdst = kdst + 32768;

  // ---- ds-read byte offsets (tile-invariant; buf parity folds to imm) ----
  unsigned ko[8];
#pragma unroll
  for (int c = 0; c < 4; ++c) {
    unsigned slot = (unsigned)((c*2 + hh) ^ (l & 7)) * 16u;
    ko[c]   = (unsigned)(quad*16384) + (unsigned)(l & 31)*128u + slot;
    ko[c+4] = ko[c] + 4096u;
  }

  const short8_t vones = {0x3F80, 0x3F80, 0x3F80, 0x3F80, 0x3F80, 0x3F80, 0x3F80, 0x3F80};
  const float SC = 0.18033688011112042f;             // (1/8) * log2(e)
  float m_run = 0.f, msc = 0.f;
  f32x16 oc0 = {}, oc1 = {}, lsum = {};

  // prologue: stage tile 0 into buffer 0
  glds16(kp,                kdst);
  glds16(kp + 8*64,         kdst + 1024);
  glds16(vp,                vdst);
  glds16(vp + (size_t)8*S_, vdst + 1024);
  const unsigned short* kn = kp + 64*64;
  const unsigned short* vn = vp + 64;
  int lt = 0;

#define ATILE(BUF)                                                              \
  do {                                                                          \
    __syncthreads();                                                            \
    if (lt < 15) {                                                              \
      glds16(kn,                kdst + ((BUF)^1)*8192);                         \
      glds16(kn + 8*64,         kdst + ((BUF)^1)*8192 + 1024);                  \
      glds16(vn,                vdst + ((BUF)^1)*8192);                         \
      glds16(vn + (size_t)8*S_, vdst + ((BUF)^1)*8192 + 1024);                  \
      kn += 4096; vn += 64;                                                     \
    }                                                                           \
    f32x16 st0 = {}, st1 = {};                                                  \
    __builtin_amdgcn_s_setprio(1);                                              \
    _Pragma("unroll")                                                           \
    for (int c = 0; c < 4; ++c) {                                               \
      short8_t kf0 = *(const short8_t*)(lds + ko[c]   + (BUF)*8192);            \
      short8_t kf1 = *(const short8_t*)(lds + ko[c+4] + (BUF)*8192);            \
      st0 = __builtin_amdgcn_mfma_f32_32x32x16_bf16(kf0, qf[c], st0, 0, 0, 0);  \
      st1 = __builtin_amdgcn_mfma_f32_32x32x16_bf16(kf1, qf[c], st1, 0, 0, 0);  \
    }                                                                           \
    __builtin_amdgcn_s_setprio(0);                                              \
    _Pragma("unroll")                                                           \
    for (int r = 0; r < 16; ++r) {                                              \
      st0[r] = __builtin_amdgcn_exp2f(fmaf(st0[r], SC, -msc));                  \
      st1[r] = __builtin_amdgcn_exp2f(fmaf(st1[r], SC, -msc));                  \
    }                                                                           \
    if (!tflag[(kbase >> 6) + lt]) {                                            \
      _Pragma("unroll")                                                         \
      for (int r = 0; r < 16; ++r) {                                            \
        int kl = kbase + lt*64 + (r & 3) + 8*(r >> 2) + 4*hh;                   \
        if (!((maskb[kl >> 3] >> (kl & 7)) & 1)) st0[r] = 0.f;                  \
        kl += 32;                                                               \
        if (!((maskb[kl >> 3] >> (kl & 7)) & 1)) st1[r] = 0.f;                  \
      }                                                                         \
    }                                                                           \
    float pmax = fmaxf(max16v(st0), max16v(st1));                               \
    short8_t pa[4];                                                             \
    {                                                                           \
      unsigned a0 = pkbf(st0[0],  st0[1]),  b0 = pkbf(st0[4],  st0[5]);         \
      unsigned a1 = pkbf(st0[2],  st0[3]),  b1 = pkbf(st0[6],  st0[7]);         \
      plswap(a0, b0); plswap(a1, b1);                                           \
      i32x4 w0 = {(int)a0, (int)a1, (int)b0, (int)b1};                          \
      pa[0] = __builtin_bit_cast(short8_t, w0);                                 \
      unsigned a2 = pkbf(st0[8],  st0[9]),  b2 = pkbf(st0[12], st0[13]);        \
      unsigned a3 = pkbf(st0[10], st0[11]), b3 = pkbf(st0[14], st0[15]);        \
      plswap(a2, b2); plswap(a3, b3);                                           \
      i32x4 w1 = {(int)a2, (int)a3, (int)b2, (int)b3};                          \
      pa[1] = __builtin_bit_cast(short8_t, w1);                                 \
      unsigned a4 = pkbf(st1[0],  st1[1]),  b4 = pkbf(st1[4],  st1[5]);         \
      unsigned a5 = pkbf(st1[2],  st1[3]),  b5 = pkbf(st1[6],  st1[7]);         \
      plswap(a4, b4); plswap(a5, b5);                                           \
      i32x4 w2 = {(int)a4, (int)a5, (int)b4, (int)b5};                          \
      pa[2] = __builtin_bit_cast(short8_t, w2);                                 \
      unsigned a6 = pkbf(st1[8],  st1[9]),  b6 = pkbf(st1[12], st1[13]);        \
      unsigned a7 = pkbf(st1[10], st1[11]), b7 = pkbf(st1[14], st1[15]);        \
      plswap(a6, b6); plswap(a7, b7);                                           \
      i32x4 w3 = {(int)a6, (int)a7, (int)b6, (int)b7};                          \
      pa[3] = __builtin_bit_cast(short8_t, w3);                                 \
    }                                                                           \
    __builtin_amdgcn_s_setprio(1);                                              \
    _Pragma("unroll")                                                           \
    for (int kc = 0; kc < 4; ++kc) {                                            \
      short8_t vf0 = *(const short8_t*)(lds + ko[kc]   + 32768 + (BUF)*8192);   \
      short8_t vf1 = *(const short8_t*)(lds + ko[kc+4] + 32768 + (BUF)*8192);   \
      oc0 = __builtin_amdgcn_mfma_f32_32x32x16_bf16(vf0, pa[kc], oc0, 0, 0, 0); \
      oc1 = __builtin_amdgcn_mfma_f32_32x32x16_bf16(vf1, pa[kc], oc1, 0, 0, 0); \
      lsum = __builtin_amdgcn_mfma_f32_32x32x16_bf16(vones, pa[kc], lsum, 0, 0, 0); \
    }                                                                           \
    __builtin_amdgcn_s_setprio(0);                                              \
    if (__any(pmax > 148.0f)) {                                                 \
      float pm = fmaxf(pmax, __shfl_xor(pmax, 32));                             \
      float smax = (__log2f(pm) + msc) / SC;                                    \
      float nm = fmaxf(m_run, smax);                                            \
      float fac = __builtin_amdgcn_exp2f((m_run - nm) * SC);                    \
      _Pragma("unroll")                                                         \
      for (int r = 0; r < 16; ++r) { oc0[r] *= fac; oc1[r] *= fac; lsum[r] *= fac; } \
      m_run = nm; msc = nm * SC;                                                \
    }                                                                           \
    ++lt;                                                                       \
  } while (0)

  for (int tp = 0; tp < 8; ++tp) {
    ATILE(0);
    ATILE(1);
  }
#undef ATILE

  // ---- merge epilogue: quad1 -> LDS, quad0 combines + stores ----
  __syncthreads();
  if (quad == 1) {
    char* obuf = lds + qw*8192 + l*128;
#pragma unroll
    for (int j = 0; j < 4; ++j) {
      f32x4 u0 = { oc0[4*j], oc0[4*j+1], oc0[4*j+2], oc0[4*j+3] };
      *(f32x4*)(obuf + ((j ^ (l & 7)) * 16)) = u0;
      f32x4 u1 = { oc1[4*j], oc1[4*j+1], oc1[4*j+2], oc1[4*j+3] };
      *(f32x4*)(obuf + (((j+4) ^ (l & 7)) * 16)) = u1;
    }
    *(float2*)(lds + 32768 + (qw*64 + l)*8) = make_float2(lsum[0], m_run);
  }
  __syncthreads();
  if (quad == 0) {
    float2 lm1 = *(const float2*)(lds + 32768 + (qw*64 + l)*8);
    float M  = fmaxf(m_run, lm1.y);
    float a0 = __builtin_amdgcn_exp2f((m_run - M) * SC);
    float a1 = __builtin_amdgcn_exp2f((lm1.y - M) * SC);
    float lc = lsum[0] * a0 + lm1.x * a1;
    float inv = 1.f / lc;
    float s0 = a0 * inv, s1 = a1 * inv;
    const char* obuf = lds + qw*8192 + l*128;
#pragma unroll
    for (int j = 0; j < 4; ++j) {
      f32x4 u0 = *(const f32x4*)(obuf + ((j ^ (l & 7)) * 16));
      oc0[4*j]   = oc0[4*j]  *s0 + u0[0]*s1;
      oc0[4*j+1] = oc0[4*j+1]*s0 + u0[1]*s1;
      oc0[4*j+2] = oc0[4*j+2]*s0 + u0[2]*s1;
      oc0[4*j+3] = oc0[4*j+3]*s0 + u0[3]*s1;
      f32x4 u1 = *(const f32x4*)(obuf + (((j+4) ^ (l & 7)) * 16));
      oc1[4*j]   = oc1[4*j]  *s0 + u1[0]*s1;
      oc1[4*j+1] = oc1[4*j+1]*s0 + u1[1]*s1;
      oc1[4*j+2] = oc1[4*j+2]*s0 + u1[2]*s1;
      oc1[4*j+3] = oc1[4*j+3]*s0 + u1[3]*s1;
    }

    unsigned short* obase = outp + ((size_t)b * S_ + q0 + (l & 31)) * C_ + h*64 + hh*8;
#pragma unroll
    for (int dt = 0; dt < 2; ++dt) {
      const f32x16& oc = dt ? oc1 : oc0;
      unsigned a0w = pkbf(oc[0],  oc[1]),  b0w = pkbf(oc[4],  oc[5]);
      unsigned a1w = pkbf(oc[2],  oc[3]),  b1w = pkbf(oc[6],  oc[7]);
      plswap(a0w, b0w); plswap(a1w, b1w);
      i32x4 w0 = {(int)a0w, (int)a1w, (int)b0w, (int)b1w};
      *(i32x4*)(obase + dt*32) = w0;
      unsigned a2w = pkbf(oc[8],  oc[9]),  b2w = pkbf(oc[12], oc[13]);
      unsigned a3w = pkbf(oc[10], oc[11]), b3w = pkbf(oc[14], oc[15]);
      plswap(a2w, b2w); plswap(a3w, b3w);
      i32x4 w1 = {(int)a2w, (int)a3w, (int)b2w, (int)b3w};
      *(i32x4*)(obase + dt*32 + 16) = w1;
    }
  }
}

// ---------------- launcher ----------------
extern "C" void kernel_launch(void* const* d_in, const int* in_sizes, int n_in,
                              void* d_out, int out_size, void* d_ws, size_t ws_size,
                              hipStream_t stream) {
  const float* hs = (const float*)d_in[0];
  const int*   msk = (const int*)d_in[1];
  const float* gw = (const float*)d_in[2];
  const float* gb = (const float*)d_in[3];
  const float* Wq = (const float*)d_in[4];
  const float* bq = (const float*)d_in[5];
  const float* Wk = (const float*)d_in[6];
  const float* bk = (const float*)d_in[7];
  const float* Wv = (const float*)d_in[8];
  const float* bv = (const float*)d_in[9];
  const float* Wo = (const float*)d_in[10];
  const float* bo = (const float*)d_in[11];

  char* ws = (char*)d_ws;
  float2* part  = (float2*)(ws + 256);
  unsigned short* wq_b = (unsigned short*)(ws + 8192);
  unsigned short* wk_b = wq_b + 1048576;
  unsigned short* wv_b = wk_b + 1048576;
  unsigned short* wo_b = wv_b + 1048576;
  unsigned short* x_b  = wo_b + 1048576;     // (B,S,C) bf16
  unsigned short* q_b  = x_b  + 4194304;     // (B,H,S,D)
  unsigned short* k_b  = q_b  + 4194304;     // (B,H,S,D)
  unsigned short* vt_b = k_b  + 4194304;     // (B,H,D,S)
  unsigned short* ao_b = vt_b + 4194304;     // (B,S,C)

  cvt_stats<<<4608, 256, 0, stream>>>(Wq, Wk, Wv, Wo, wq_b, hs, part);
  normt<<<1024, 256, 0, stream>>>(hs, gw, gb, part, x_b);

  gemm_qk<<<512, 256, 0, stream>>>(x_b, wq_b, bq, bk, q_b);
  gemm_nt<1><<<512, 256, 0, stream>>>(wv_b, x_b, bv, nullptr, vt_b, 32);

  attn_kernel<<<512, 512, 0, stream>>>(q_b, k_b, vt_b, msk, ao_b);

  gemm_nt<2><<<512, 256, 0, stream>>>(wo_b, ao_b, bo, hs, d_out, 32);
}